// Round 6
// baseline (1809.115 us; speedup 1.0000x reference)
//
#include <hip/hip_runtime.h>
#include <hip/hip_bf16.h>

typedef float f32x4 __attribute__((ext_vector_type(4)));
typedef __bf16 bf16x8 __attribute__((ext_vector_type(8)));
typedef unsigned short u16x8 __attribute__((ext_vector_type(8)));
typedef unsigned short u16;

// LDS map (dynamic): z 32KB | nrm 2KB | h [32][65]f32 8.3KB | scl 2KB | gates 64B
// enc1 x-stage (4KB) overlays nrm+h. Total 45248 B -> 3 blocks/CU.
#define SMEM_BYTES 45248
#define Z_OFF 0
#define NRM_OFF 32768
#define H_OFF 34816
#define SCL_OFF 43136
#define GATE_OFF 45184

__device__ __forceinline__ u16 f2bf(float f) {        // native v_cvt_pk_bf16_f32 (RNE)
  __bf16 h = (__bf16)f;
  return __builtin_bit_cast(u16, h);
}
__device__ __forceinline__ float bf2f(u16 s) {
  return __uint_as_float(((unsigned int)s) << 16);
}
__device__ __forceinline__ float gelu_f(float x) {
  return 0.5f * x * (1.0f + erff(x * 0.70710678118654752f)); // erf GELU
}

// ---------------- merged weight conversion ----------------
__global__ void cvt_all(const float* __restrict__ e1, const float* __restrict__ e2,
                        const float* __restrict__ e3, const float* __restrict__ d1,
                        const float* __restrict__ d2, const float* __restrict__ d3,
                        const float* __restrict__ mx, u16* __restrict__ dst)
{
  int i = blockIdx.x * blockDim.x + threadIdx.x;
  int stride = gridDim.x * blockDim.x;
  for (; i < 3145728; i += stride) {
    float v;
    if (i < 524288)        v = e1[i];
    else if (i < 786432)   v = e2[i - 524288];
    else if (i < 1048576)  v = e3[i - 786432];
    else if (i < 1310720)  v = d1[i - 1048576];
    else if (i < 1572864)  v = d2[i - 1310720];
    else if (i < 2097152)  v = d3[i - 1572864];
    else {
      // mix_w [L,16,16,32,32] (l,bi,j,e,d) -> W[l][o=bi*32+e][k=j*32+d]
      int j = i - 2097152;
      int l = j >> 18, rem = j & 262143;
      int o = rem >> 9, k = rem & 511;
      int bi = o >> 5, e = o & 31, jj = k >> 5, dd = k & 31;
      v = mx[(((l * 16 + bi) * 16 + jj) * 32 + e) * 32 + dd];
    }
    dst[i] = f2bf(v);
  }
}

// ---------------- in-place strip GEMM: z(32x512) x W^T ----------------
// 4 waves; wave wid owns cols [wid*128, wid*128+128).
// EPI: 0 gelu+bias->z ; 1 bias->z ; 2 latent combine->z ; 3 bias->f32 global
template<int EPI>
__device__ __forceinline__ void gemm512(char* __restrict__ smem,
    const u16* __restrict__ W, const float* __restrict__ bias,
    float* __restrict__ outG, int nOff, int m0)
{
  __syncthreads();                       // previous phase's z writes visible
  const int tid = threadIdx.x;
  const int lane = tid & 63;
  const int wid = tid >> 6;
  const int c0 = wid << 7;
  const int r16 = lane & 15;
  const int kg = (lane >> 4) << 3;
  const int sw = (r16 & 7) << 4;
  char* z = smem + Z_OFF;

  const u16* wrow[8];                    // hoisted B row bases
  #pragma unroll
  for (int nt = 0; nt < 8; ++nt)
    wrow[nt] = W + (size_t)(nOff + c0 + nt * 16 + r16) * 512 + kg;
  const char* arow[2];
  #pragma unroll
  for (int mt = 0; mt < 2; ++mt)
    arow[mt] = z + (mt * 16 + r16) * 1024;

  f32x4 acc[2][8] = {};
  #pragma unroll 2
  for (int ks = 0; ks < 16; ++ks) {
    const int kb = (ks << 6) | (kg << 1);
    bf16x8 av[2], bv[8];
    #pragma unroll
    for (int nt = 0; nt < 8; ++nt)
      bv[nt] = *(const bf16x8*)(wrow[nt] + (ks << 5));
    #pragma unroll
    for (int mt = 0; mt < 2; ++mt)
      av[mt] = *(const bf16x8*)(arow[mt] + (kb ^ sw));
    __builtin_amdgcn_s_setprio(1);
    #pragma unroll
    for (int mt = 0; mt < 2; ++mt)
      #pragma unroll
      for (int nt = 0; nt < 8; ++nt)
        acc[mt][nt] = __builtin_amdgcn_mfma_f32_16x16x32_bf16(av[mt], bv[nt], acc[mt][nt], 0, 0, 0);
    __builtin_amdgcn_s_setprio(0);
  }

  __syncthreads();                       // all waves done reading z (in-place safety)

  const float* scl = (const float*)(smem + SCL_OFF);
  const float* gateL = (const float*)(smem + GATE_OFF);
  #pragma unroll
  for (int nt = 0; nt < 8; ++nt) {
    const int col = c0 + nt * 16 + r16;
    float bv_ = 0.f, gate = 0.f;
    if constexpr (EPI == 0 || EPI == 1 || EPI == 3) bv_ = bias[nOff + col];
    if constexpr (EPI == 2) gate = gateL[col >> 5];
    #pragma unroll
    for (int mt = 0; mt < 2; ++mt) {
      #pragma unroll
      for (int r = 0; r < 4; ++r) {
        const int row = mt * 16 + ((lane >> 4) << 2) + r;
        float v = acc[mt][nt][r];
        if constexpr (EPI == 3) {
          outG[(size_t)(m0 + row) * 1024 + nOff + col] = v + bv_;
        } else {
          char* zp = z + row * 1024 + ((col << 1) ^ ((row & 7) << 4));
          if constexpr (EPI == 0)      *(u16*)zp = f2bf(gelu_f(v + bv_));
          else if constexpr (EPI == 1) *(u16*)zp = f2bf(v + bv_);
          else {
            float sc = scl[row * 16 + (col >> 5)];
            float zo = bf2f(*(const u16*)zp);
            *(u16*)zp = f2bf(zo * (1.f + sc) + gate * v);
          }
        }
      }
    }
  }
}

// ---------------- bundle norms -> MLP -> softplus scales (+gates) ----------------
__device__ __forceinline__ void norm_phase(char* __restrict__ smem,
    const float* __restrict__ w1, const float* __restrict__ b1,
    const float* __restrict__ w2, const float* __restrict__ b2,
    const float* __restrict__ w3, const float* __restrict__ gb)
{
  __syncthreads();
  const int tid = threadIdx.x;
  const int lane = tid & 63;
  const int wv = tid >> 6;
  float* nrm = (float*)(smem + NRM_OFF);
  float* h   = (float*)(smem + H_OFF);       // [32][65] f32
  float* scl = (float*)(smem + SCL_OFF);
  float* gateL = (float*)(smem + GATE_OFF);
  const char* z = smem + Z_OFF;

  // N1: one wave per row (conflict-free full-row read), 8 passes
  #pragma unroll
  for (int p = 0; p < 8; ++p) {
    const int row = p * 4 + wv;
    u16x8 v = *(const u16x8*)(z + row * 1024 + ((lane << 4) ^ ((row & 7) << 4)));
    float ss = 0.f;
    #pragma unroll
    for (int j = 0; j < 8; ++j) { float f = bf2f(v[j]); ss += f * f; }
    ss += __shfl_xor(ss, 1);
    ss += __shfl_xor(ss, 2);
    if ((lane & 3) == 0) {
      const int bundle = (lane >> 2) ^ ((row >> 2) & 1);   // XOR-aware chunk->bundle
      nrm[row * 16 + bundle] = sqrtf(ss) + 1e-8f;
    }
  }
  if (tid < 16) gateL[tid] = 1.f / (1.f + expf(-gb[tid]));
  __syncthreads();

  // N2: h = gelu(nrm @ w1^T + b1); wave wv owns rows wv*8..wv*8+7, col j=lane
  {
    const int j = lane;
    float a[8];
    #pragma unroll
    for (int p = 0; p < 8; ++p) a[p] = b1[j];
    #pragma unroll
    for (int i = 0; i < 16; ++i) {
      float w = w1[j * 16 + i];
      #pragma unroll
      for (int p = 0; p < 8; ++p) a[p] += nrm[(wv * 8 + p) * 16 + i] * w;
    }
    #pragma unroll
    for (int p = 0; p < 8; ++p) h[(wv * 8 + p) * 65 + j] = gelu_f(a[p]);
  }
  __syncthreads();
  // N3: h = gelu(h @ w2^T + b2) (wave-local rows; reads precede writes in-wave)
  {
    const int j = lane;
    float a[8];
    #pragma unroll
    for (int p = 0; p < 8; ++p) a[p] = b2[j];
    for (int k = 0; k < 64; ++k) {
      float w = w2[j * 64 + k];
      #pragma unroll
      for (int p = 0; p < 8; ++p) a[p] += h[(wv * 8 + p) * 65 + k] * w;
    }
    #pragma unroll
    for (int p = 0; p < 8; ++p) h[(wv * 8 + p) * 65 + j] = gelu_f(a[p]);
  }
  __syncthreads();
  // N4: scl = softplus(h @ w3^T): 32 rows x 16 bundles, 2 per thread
  {
    const int b = tid & 15;
    const int r0 = tid >> 4;               // 0..15
    float a0 = 0.f, a1 = 0.f;
    for (int k = 0; k < 64; ++k) {
      float w = w3[b * 64 + k];
      a0 += h[r0 * 65 + k] * w;
      a1 += h[(r0 + 16) * 65 + k] * w;
    }
    a0 = (a0 > 20.f) ? a0 : log1pf(expf(a0));
    a1 = (a1 > 20.f) ? a1 : log1pf(expf(a1));
    scl[r0 * 16 + b] = a0;
    scl[(r0 + 16) * 16 + b] = a1;
  }
  __syncthreads();
}

// ---------------- fused network: one block per 32-row strip ----------------
__global__ __launch_bounds__(256, 2)
void ugn_mega(const float* __restrict__ x,
              const float* __restrict__ enc_b1, const float* __restrict__ enc_b2,
              const float* __restrict__ enc_b3,
              const float* __restrict__ mlp1_w, const float* __restrict__ mlp1_b,
              const float* __restrict__ mlp2_w, const float* __restrict__ mlp2_b,
              const float* __restrict__ mlp3_w, const float* __restrict__ gate_b,
              const float* __restrict__ dec_b1, const float* __restrict__ dec_b2,
              const float* __restrict__ dec_b3,
              const u16* __restrict__ wE1, const u16* __restrict__ wE2,
              const u16* __restrict__ wE3, const u16* __restrict__ wMix,
              const u16* __restrict__ wD1, const u16* __restrict__ wD2,
              const u16* __restrict__ wD3, float* __restrict__ out)
{
  extern __shared__ char smem[];
  const int m0 = blockIdx.x << 5;          // 32-row strip
  const int tid = threadIdx.x;
  const int lane = tid & 63;
  const int wid = tid >> 6;
  const int c0 = wid << 7;
  const int r16 = lane & 15;
  const int kg = (lane >> 4) << 3;
  const int sw = (r16 & 7) << 4;

  // ===== enc1: z = gelu(x @ wE1^T + b1), K=1024 in 16 chunks =====
  {
    char* stage = smem + NRM_OFF;          // 4KB [32][64] bf16 swizzled
    char* z = smem + Z_OFF;
    const float* xs = x + (size_t)m0 * 1024;
    const int xr = tid >> 3;               // 0..31
    const int kp = (tid & 7) << 3;         // 0..56
    const u16* wrow[8];
    #pragma unroll
    for (int nt = 0; nt < 8; ++nt)
      wrow[nt] = wE1 + (size_t)(c0 + nt * 16 + r16) * 1024 + kg;

    float4 v0 = *(const float4*)(xs + (size_t)xr * 1024 + kp);
    float4 v1 = *(const float4*)(xs + (size_t)xr * 1024 + kp + 4);
    f32x4 acc[2][8] = {};
    for (int c = 0; c < 16; ++c) {
      u16x8 u;
      u[0] = f2bf(v0.x); u[1] = f2bf(v0.y); u[2] = f2bf(v0.z); u[3] = f2bf(v0.w);
      u[4] = f2bf(v1.x); u[5] = f2bf(v1.y); u[6] = f2bf(v1.z); u[7] = f2bf(v1.w);
      *(u16x8*)(stage + xr * 128 + ((kp << 1) ^ ((xr & 7) << 4))) = u;
      __syncthreads();
      if (c < 15) {                        // T14: issue next chunk's loads early
        const float* src = xs + (size_t)xr * 1024 + (c + 1) * 64 + kp;
        v0 = *(const float4*)src;
        v1 = *(const float4*)(src + 4);
      }
      #pragma unroll
      for (int ks = 0; ks < 2; ++ks) {
        bf16x8 av[2], bv[8];
        #pragma unroll
        for (int nt = 0; nt < 8; ++nt)
          bv[nt] = *(const bf16x8*)(wrow[nt] + c * 64 + ks * 32);
        #pragma unroll
        for (int mt = 0; mt < 2; ++mt)
          av[mt] = *(const bf16x8*)(stage + (mt * 16 + r16) * 128 + (((ks << 6) | (kg << 1)) ^ sw));
        __builtin_amdgcn_s_setprio(1);
        #pragma unroll
        for (int mt = 0; mt < 2; ++mt)
          #pragma unroll
          for (int nt = 0; nt < 8; ++nt)
            acc[mt][nt] = __builtin_amdgcn_mfma_f32_16x16x32_bf16(av[mt], bv[nt], acc[mt][nt], 0, 0, 0);
        __builtin_amdgcn_s_setprio(0);
      }
      __syncthreads();
    }
    #pragma unroll
    for (int nt = 0; nt < 8; ++nt) {
      const int col = c0 + nt * 16 + r16;
      const float bb = enc_b1[col];
      #pragma unroll
      for (int mt = 0; mt < 2; ++mt) {
        #pragma unroll
        for (int r = 0; r < 4; ++r) {
          const int row = mt * 16 + ((lane >> 4) << 2) + r;
          *(u16*)(z + row * 1024 + ((col << 1) ^ ((row & 7) << 4))) =
              f2bf(gelu_f(acc[mt][nt][r] + bb));
        }
      }
    }
  }

  // ===== enc2 / enc3 (in-place) =====
  gemm512<0>(smem, wE2, enc_b2, nullptr, 0, m0);
  gemm512<1>(smem, wE3, enc_b3, nullptr, 0, m0);

  // ===== 4 latent layers =====
  #pragma unroll 1
  for (int l = 0; l < 4; ++l) {
    norm_phase(smem, mlp1_w + l * 1024, mlp1_b + l * 64,
               mlp2_w + l * 4096, mlp2_b + l * 64,
               mlp3_w + l * 1024, gate_b + l * 16);
    gemm512<2>(smem, wMix + (size_t)l * 262144, nullptr, nullptr, 0, m0);
  }

  // ===== decoder =====
  gemm512<0>(smem, wD1, dec_b1, nullptr, 0, m0);
  gemm512<0>(smem, wD2, dec_b2, nullptr, 0, m0);
  gemm512<3>(smem, wD3, dec_b3, out, 0, m0);
  gemm512<3>(smem, wD3, dec_b3, out, 512, m0);
}

// ---------------- launch ----------------
extern "C" void kernel_launch(void* const* d_in, const int* in_sizes, int n_in,
                              void* d_out, int out_size, void* d_ws, size_t ws_size,
                              hipStream_t stream)
{
  (void)in_sizes; (void)n_in; (void)out_size; (void)ws_size;
  const float* x      = (const float*)d_in[0];
  const float* enc_w1 = (const float*)d_in[1];
  const float* enc_b1 = (const float*)d_in[2];
  const float* enc_w2 = (const float*)d_in[3];
  const float* enc_b2 = (const float*)d_in[4];
  const float* enc_w3 = (const float*)d_in[5];
  const float* enc_b3 = (const float*)d_in[6];
  const float* mlp1_w = (const float*)d_in[7];
  const float* mlp1_b = (const float*)d_in[8];
  const float* mlp2_w = (const float*)d_in[9];
  const float* mlp2_b = (const float*)d_in[10];
  const float* mlp3_w = (const float*)d_in[11];
  const float* mix_w  = (const float*)d_in[12];
  const float* gate_b = (const float*)d_in[13];
  const float* dec_w1 = (const float*)d_in[14];
  const float* dec_b1 = (const float*)d_in[15];
  const float* dec_w2 = (const float*)d_in[16];
  const float* dec_b2 = (const float*)d_in[17];
  const float* dec_w3 = (const float*)d_in[18];
  const float* dec_b3 = (const float*)d_in[19];

  u16* wBase = (u16*)d_ws;
  u16* wE1 = wBase;
  u16* wE2 = wE1 + 524288;
  u16* wE3 = wE2 + 262144;
  u16* wD1 = wE3 + 262144;
  u16* wD2 = wD1 + 262144;
  u16* wD3 = wD2 + 262144;
  u16* wMix = wD3 + 524288;

  cvt_all<<<512, 256, 0, stream>>>(enc_w1, enc_w2, enc_w3, dec_w1, dec_w2, dec_w3,
                                   mix_w, wBase);

  static int smemSet = 0;
  if (!smemSet) {
    hipFuncSetAttribute(reinterpret_cast<const void*>(&ugn_mega),
                        hipFuncAttributeMaxDynamicSharedMemorySize, SMEM_BYTES);
    smemSet = 1;
  }

  ugn_mega<<<2048, 256, SMEM_BYTES, stream>>>(
      x, enc_b1, enc_b2, enc_b3, mlp1_w, mlp1_b, mlp2_w, mlp2_b, mlp3_w, gate_b,
      dec_b1, dec_b2, dec_b3, wE1, wE2, wE3, wMix, wD1, wD2, wD3, (float*)d_out);
}